// Round 4
// baseline (690.661 us; speedup 1.0000x reference)
//
#include <hip/hip_runtime.h>
#include <math.h>

#define NB 8
#define PP 2048
#define DD 64
#define EPSF 1e-3f
#define RCPE 1000.0f
#define TMAX 10
#define THRESHF 0.1f
#define NEG_INF (-1e30f)
#define QSCALE 32767.5f                 // cost in [0,2] -> u16
#define S_DEQ  (1.0f / 32767.5f)

__device__ __forceinline__ float waveAllMax(float v) {
#pragma unroll
    for (int m = 1; m < 64; m <<= 1) v = fmaxf(v, __shfl_xor(v, m, 64));
    return v;
}
__device__ __forceinline__ float waveAllSum(float v) {
#pragma unroll
    for (int m = 1; m < 64; m <<= 1) v += __shfl_xor(v, m, 64);
    return v;
}
__device__ __forceinline__ void unpack8(uint4 q, float* c) {
    c[0] = (float)(q.x & 0xffffu) * S_DEQ; c[1] = (float)(q.x >> 16) * S_DEQ;
    c[2] = (float)(q.y & 0xffffu) * S_DEQ; c[3] = (float)(q.y >> 16) * S_DEQ;
    c[4] = (float)(q.z & 0xffffu) * S_DEQ; c[5] = (float)(q.z >> 16) * S_DEQ;
    c[6] = (float)(q.w & 0xffffu) * S_DEQ; c[7] = (float)(q.w >> 16) * S_DEQ;
}

// ---- init: zero u, v, conv, out --------------------------------------------
__global__ void init_kernel(float* u, float* v, int* conv, float* out) {
    int t = blockIdx.x * 256 + threadIdx.x;   // 16384 threads
    u[t] = 0.0f; v[t] = 0.0f;
    if (t == 0) *conv = 0;
    if (t < NB) out[t] = 0.0f;
}

// ---- L2 normalize: one wave per row ----------------------------------------
__global__ void norm_kernel(const float* __restrict__ a, const float* __restrict__ b,
                            float* __restrict__ an, float* __restrict__ bn) {
    int wave = (blockIdx.x * blockDim.x + threadIdx.x) >> 6;
    int lane = threadIdx.x & 63;
    const float* src; float* dst; int row;
    if (wave < NB * PP) { src = a; dst = an; row = wave; }
    else                { src = b; dst = bn; row = wave - NB * PP; }
    float x = src[(size_t)row * DD + lane];
    float ss = waveAllSum(x * x);
    float r = 1.0f / fmaxf(sqrtf(ss), 1e-12f);
    dst[(size_t)row * DD + lane] = x * r;
}

// ---- cost GEMM: 128x128 tile, 8x8 acc/thread; quant store + partial sums ---
#define CT 132   // padded LDS stride
__global__ __launch_bounds__(256) void cost_kernel(const float* __restrict__ an,
                                                   const float* __restrict__ bn,
                                                   unsigned short* __restrict__ C16,
                                                   float* __restrict__ rpart,
                                                   float* __restrict__ cpart) {
    int b  = blockIdx.z;
    int i0 = blockIdx.y * 128;
    int j0 = blockIdx.x * 128;
    __shared__ float As[64][CT];   // [k][i]
    __shared__ float Bs[64][CT];   // [k][j]
    __shared__ float cs[16][128];  // col-partial staging
    int t = threadIdx.x;
    {
        int r  = t >> 1;
        int kh = (t & 1) * 32;
        const float4* pa = (const float4*)&an[((size_t)b * PP + i0 + r) * DD + kh];
        const float4* pb = (const float4*)&bn[((size_t)b * PP + j0 + r) * DD + kh];
#pragma unroll
        for (int q = 0; q < 8; ++q) {
            float4 va = pa[q]; float4 vb = pb[q];
            int k = kh + q * 4;
            As[k+0][r] = va.x; As[k+1][r] = va.y; As[k+2][r] = va.z; As[k+3][r] = va.w;
            Bs[k+0][r] = vb.x; Bs[k+1][r] = vb.y; Bs[k+2][r] = vb.z; Bs[k+3][r] = vb.w;
        }
    }
    __syncthreads();
    int tx = t & 15, ty = t >> 4;
    float acc[8][8] = {};
#pragma unroll 4
    for (int k = 0; k < 64; ++k) {
        float4 a0 = *(const float4*)&As[k][ty * 8];
        float4 a1 = *(const float4*)&As[k][ty * 8 + 4];
        float4 b0 = *(const float4*)&Bs[k][tx * 8];
        float4 b1 = *(const float4*)&Bs[k][tx * 8 + 4];
        float aa[8] = {a0.x, a0.y, a0.z, a0.w, a1.x, a1.y, a1.z, a1.w};
        float bb[8] = {b0.x, b0.y, b0.z, b0.w, b1.x, b1.y, b1.z, b1.w};
#pragma unroll
        for (int r = 0; r < 8; ++r)
#pragma unroll
            for (int c = 0; c < 8; ++c)
                acc[r][c] += aa[r] * bb[c];
    }
    // epilogue: quant store + row partials (reduce over tx) + col partials
    int lane = t & 63;
#pragma unroll
    for (int r = 0; r < 8; ++r) {
        int row = i0 + ty * 8 + r;
        ushort4 q0, q1;
        float cc[8];
#pragma unroll
        for (int c = 0; c < 8; ++c)
            cc[c] = fminf(fmaxf(1.0f - acc[r][c], 0.0f), 2.0f);
        q0.x = (unsigned short)__float2uint_rn(cc[0] * QSCALE);
        q0.y = (unsigned short)__float2uint_rn(cc[1] * QSCALE);
        q0.z = (unsigned short)__float2uint_rn(cc[2] * QSCALE);
        q0.w = (unsigned short)__float2uint_rn(cc[3] * QSCALE);
        q1.x = (unsigned short)__float2uint_rn(cc[4] * QSCALE);
        q1.y = (unsigned short)__float2uint_rn(cc[5] * QSCALE);
        q1.z = (unsigned short)__float2uint_rn(cc[6] * QSCALE);
        q1.w = (unsigned short)__float2uint_rn(cc[7] * QSCALE);
        *(ushort4*)&C16[((size_t)b * PP + row) * PP + j0 + tx * 8]     = q0;
        *(ushort4*)&C16[((size_t)b * PP + row) * PP + j0 + tx * 8 + 4] = q1;
        // row partial (sum of S = dot over this block's 128 cols)
        float rs = acc[r][0] + acc[r][1] + acc[r][2] + acc[r][3]
                 + acc[r][4] + acc[r][5] + acc[r][6] + acc[r][7];
#pragma unroll
        for (int m = 1; m < 16; m <<= 1) rs += __shfl_xor(rs, m, 64);
        if ((lane & 15) == 0)
            rpart[(size_t)blockIdx.x * (NB * PP) + b * PP + row] = rs;
    }
#pragma unroll
    for (int c = 0; c < 8; ++c) {
        float csm = acc[0][c] + acc[1][c] + acc[2][c] + acc[3][c]
                  + acc[4][c] + acc[5][c] + acc[6][c] + acc[7][c];
        cs[ty][tx * 8 + c] = csm;
    }
    __syncthreads();
    if (t < 128) {
        float tot = 0.0f;
#pragma unroll
        for (int g = 0; g < 16; ++g) tot += cs[g][t];
        cpart[(size_t)blockIdx.y * (NB * PP) + b * PP + j0 + t] = tot;
    }
}

// ---- combine partial sums -> rowS, colS ------------------------------------
__global__ void sums_combine_kernel(const float* __restrict__ rpart,
                                    const float* __restrict__ cpart,
                                    float* __restrict__ rowS, float* __restrict__ colS) {
    int idx = blockIdx.x * 256 + threadIdx.x;   // 64 blocks -> 16384
    float rs = 0.0f, csf = 0.0f;
#pragma unroll
    for (int k = 0; k < 16; ++k) {
        rs  += rpart[(size_t)k * (NB * PP) + idx];
        csf += cpart[(size_t)k * (NB * PP) + idx];
    }
    rowS[idx] = rs; colS[idx] = csf;
}

// ---- weights: l1norm(clip(l1norm(mean(S)))) then store eps*log(w + 1e-8) ---
__device__ __forceinline__ float blockReduceSum256(float v, float* sh) {
    v = waveAllSum(v);
    int lane = threadIdx.x & 63, w = threadIdx.x >> 6;
    if (lane == 0) sh[w] = v;
    __syncthreads();
    float r = sh[0] + sh[1] + sh[2] + sh[3];
    __syncthreads();
    return r;
}

__global__ void weights_kernel(const float* __restrict__ rowS, const float* __restrict__ colS,
                               float* __restrict__ elm, float* __restrict__ eln) {
    __shared__ float sh[4];
    int b = blockIdx.x & 7;
    bool isB = blockIdx.x >= 8;
    const float* src = (isB ? colS : rowS) + b * PP;
    float* dst = (isB ? eln : elm) + b * PP;
    int tid = threadIdx.x;
    float x[8];
    float sabs = 0.0f;
#pragma unroll
    for (int q = 0; q < 8; ++q) {
        x[q] = src[tid + q * 256] * (1.0f / (float)PP);
        sabs += fabsf(x[q]);
    }
    sabs = blockReduceSum256(sabs, sh);
    float inv1 = 1.0f / fmaxf(sabs, 1e-12f);
    float spos = 0.0f;
#pragma unroll
    for (int q = 0; q < 8; ++q) {
        x[q] = fmaxf(x[q] * inv1, 0.0f);
        spos += x[q];
    }
    spos = blockReduceSum256(spos, sh);
    float inv2 = 1.0f / fmaxf(spos, 1e-12f);
#pragma unroll
    for (int q = 0; q < 8; ++q)
        dst[tid + q * 256] = EPSF * logf(x[q] * inv2 + 1e-8f);
}

// ---- fused Sinkhorn sweep: u-update (row LSE) + v column partials ----------
// Block = 16-row chunk (4 waves x 4 rows). C read ONCE per iteration.
__global__ __launch_bounds__(256) void uv_pass(const unsigned short* __restrict__ C16,
        const float* __restrict__ v, const float* __restrict__ elm,
        float* __restrict__ u, float* __restrict__ du,
        float* __restrict__ vmp, float* __restrict__ vsp, const int* __restrict__ conv) {
    if (*conv) return;
    int blk = blockIdx.x;           // 0..1023 = b*128 + rc
    int b   = blk >> 7;
    int rc  = blk & 127;
    int w = threadIdx.x >> 6, lane = threadIdx.x & 63;
    int row0 = rc * 16 + w * 4;
    const float* vb = v + b * PP;
    float mcol[32], scol[32];
#pragma unroll
    for (int e = 0; e < 32; ++e) { mcol[e] = NEG_INF; scol[e] = 0.0f; }

    for (int r = 0; r < 4; ++r) {
        int row = row0 + r;
        const uint4* cp = (const uint4*)(C16 + ((size_t)b * PP + row) * PP);
        float cr[32];
        {
            uint4 q0 = cp[lane], q1 = cp[64 + lane], q2 = cp[128 + lane], q3 = cp[192 + lane];
            unpack8(q0, cr); unpack8(q1, cr + 8); unpack8(q2, cr + 16); unpack8(q3, cr + 24);
        }
        // phase 1: row max of (v - c)
        float lm = NEG_INF;
#pragma unroll
        for (int g = 0; g < 4; ++g) {
            float4 v0 = *(const float4*)(vb + g * 512 + lane * 8);
            float4 v1 = *(const float4*)(vb + g * 512 + lane * 8 + 4);
            lm = fmaxf(lm, fmaxf(fmaxf(v0.x - cr[g*8+0], v0.y - cr[g*8+1]),
                                 fmaxf(v0.z - cr[g*8+2], v0.w - cr[g*8+3])));
            lm = fmaxf(lm, fmaxf(fmaxf(v1.x - cr[g*8+4], v1.y - cr[g*8+5]),
                                 fmaxf(v1.z - cr[g*8+6], v1.w - cr[g*8+7])));
        }
        float m = waveAllMax(lm);
        // phase 2: exp-sum (v reload hits L1)
        float s = 0.0f;
#pragma unroll
        for (int g = 0; g < 4; ++g) {
            float4 v0 = *(const float4*)(vb + g * 512 + lane * 8);
            float4 v1 = *(const float4*)(vb + g * 512 + lane * 8 + 4);
            s += __expf((v0.x - cr[g*8+0] - m) * RCPE) + __expf((v0.y - cr[g*8+1] - m) * RCPE)
               + __expf((v0.z - cr[g*8+2] - m) * RCPE) + __expf((v0.w - cr[g*8+3] - m) * RCPE)
               + __expf((v1.x - cr[g*8+4] - m) * RCPE) + __expf((v1.y - cr[g*8+5] - m) * RCPE)
               + __expf((v1.z - cr[g*8+6] - m) * RCPE) + __expf((v1.w - cr[g*8+7] - m) * RCPE);
        }
        s = waveAllSum(s);
        float ui = elm[b * PP + row] - m - EPSF * logf(s);
        if (lane == 0) {
            int gi = b * PP + row;
            du[gi] = fabsf(ui - u[gi]);
            u[gi] = ui;
        }
        // column online-LSE update with new u_i
#pragma unroll
        for (int e = 0; e < 32; ++e) {
            float tv = ui - cr[e];
            float nm = fmaxf(mcol[e], tv);
            scol[e] = scol[e] * __expf((mcol[e] - nm) * RCPE) + __expf((tv - nm) * RCPE);
            mcol[e] = nm;
        }
    }
    // cross-wave merge of per-column (m,s)
    __shared__ float shM[3][PP];
    __shared__ float shS[3][PP];
    if (w > 0) {
#pragma unroll
        for (int g = 0; g < 4; ++g) {
            int col = g * 512 + lane * 8;
            *(float4*)&shM[w-1][col]     = make_float4(mcol[g*8+0], mcol[g*8+1], mcol[g*8+2], mcol[g*8+3]);
            *(float4*)&shM[w-1][col + 4] = make_float4(mcol[g*8+4], mcol[g*8+5], mcol[g*8+6], mcol[g*8+7]);
            *(float4*)&shS[w-1][col]     = make_float4(scol[g*8+0], scol[g*8+1], scol[g*8+2], scol[g*8+3]);
            *(float4*)&shS[w-1][col + 4] = make_float4(scol[g*8+4], scol[g*8+5], scol[g*8+6], scol[g*8+7]);
        }
    }
    __syncthreads();
    if (w == 0) {
#pragma unroll
        for (int g = 0; g < 4; ++g) {
            float Mo[8], So[8];
#pragma unroll
            for (int e = 0; e < 8; ++e) {
                int col = g * 512 + lane * 8 + e;
                float M = mcol[g*8+e], S = scol[g*8+e];
#pragma unroll
                for (int ww = 0; ww < 3; ++ww) {
                    float m2 = shM[ww][col], s2 = shS[ww][col];
                    float nm = fmaxf(M, m2);
                    S = S * __expf((M - nm) * RCPE) + s2 * __expf((m2 - nm) * RCPE);
                    M = nm;
                }
                Mo[e] = M; So[e] = S;
            }
            size_t o = (size_t)blk * PP + g * 512 + lane * 8;
            *(float4*)&vmp[o]     = make_float4(Mo[0], Mo[1], Mo[2], Mo[3]);
            *(float4*)&vmp[o + 4] = make_float4(Mo[4], Mo[5], Mo[6], Mo[7]);
            *(float4*)&vsp[o]     = make_float4(So[0], So[1], So[2], So[3]);
            *(float4*)&vsp[o + 4] = make_float4(So[4], So[5], So[6], So[7]);
        }
    }
}

// ---- v combine (128 chunks) + err reduce + conv update ---------------------
__global__ __launch_bounds__(256) void v_combine_err(const float* __restrict__ vmp,
        const float* __restrict__ vsp, const float* __restrict__ eln,
        float* __restrict__ v, const float* __restrict__ du, int* __restrict__ conv) {
    if (*conv) return;
    int jg = blockIdx.x * 256 + threadIdx.x;  // 64 blocks -> 16384
    int b = jg >> 11, j = jg & (PP - 1);
    const float* mp = vmp + (size_t)(b * 128) * PP + j;
    const float* sp = vsp + (size_t)(b * 128) * PP + j;
    float M = NEG_INF, S = 0.0f;
    for (int k = 0; k < 128; ++k) {
        float m2 = mp[(size_t)k * PP];
        float s2 = sp[(size_t)k * PP];
        float nm = fmaxf(M, m2);
        S = S * __expf((M - nm) * RCPE) + s2 * __expf((m2 - nm) * RCPE);
        M = nm;
    }
    v[jg] = eln[jg] - M - EPSF * logf(S);
    if (blockIdx.x == 0) {
        __shared__ float sh[4];
        int t = threadIdx.x, lane = t & 63, w = t >> 6;
        float sacc = 0.0f;
#pragma unroll
        for (int q = 0; q < 64; ++q) sacc += du[t + q * 256];
        sacc = waveAllSum(sacc);
        if (lane == 0) sh[w] = sacc;
        __syncthreads();
        if (t == 0) {
            float tot = sh[0] + sh[1] + sh[2] + sh[3];
            if (tot * (1.0f / (float)NB) < THRESHF) *conv = 1;
        }
    }
}

// ---- final: D[b] = sum_ij exp((u_i + v_j - C_ij)/eps) * C_ij ---------------
__global__ __launch_bounds__(256) void emd_kernel(const unsigned short* __restrict__ C16,
        const float* __restrict__ u, const float* __restrict__ v, float* __restrict__ out) {
    __shared__ float sh[4];
    int wv = threadIdx.x >> 6, lane = threadIdx.x & 63;
    int bi = blockIdx.x * 4 + wv;
    int b = bi >> 11;
    const uint4*  row = (const uint4*)(C16 + (size_t)bi * PP);
    const float4* vb  = (const float4*)(v + b * PP);
    float ui = u[bi];
    float s = 0.0f;
#pragma unroll
    for (int g = 0; g < 4; ++g) {
        int idx = g * 64 + lane;
        uint4  q  = row[idx];
        float4 v0 = vb[idx * 2];
        float4 v1 = vb[idx * 2 + 1];
        float c[8];
        c[0] = (float)(q.x & 0xffffu) * S_DEQ; c[1] = (float)(q.x >> 16) * S_DEQ;
        c[2] = (float)(q.y & 0xffffu) * S_DEQ; c[3] = (float)(q.y >> 16) * S_DEQ;
        c[4] = (float)(q.z & 0xffffu) * S_DEQ; c[5] = (float)(q.z >> 16) * S_DEQ;
        c[6] = (float)(q.w & 0xffffu) * S_DEQ; c[7] = (float)(q.w >> 16) * S_DEQ;
        float vv[8] = {v0.x, v0.y, v0.z, v0.w, v1.x, v1.y, v1.z, v1.w};
#pragma unroll
        for (int k = 0; k < 8; ++k)
            s += __expf((ui + vv[k] - c[k]) * RCPE) * c[k];
    }
    s = waveAllSum(s);
    if (lane == 0) sh[wv] = s;
    __syncthreads();
    if (threadIdx.x == 0) atomicAdd(&out[b], sh[0] + sh[1] + sh[2] + sh[3]);
}

extern "C" void kernel_launch(void* const* d_in, const int* in_sizes, int n_in,
                              void* d_out, int out_size, void* d_ws, size_t ws_size,
                              hipStream_t stream) {
    const float* a = (const float*)d_in[0];
    const float* b = (const float*)d_in[1];
    float* out = (float*)d_out;

    char* ws = (char*)d_ws;
    size_t off = 0;
    const size_t szC16  = (size_t)NB * PP * PP * 2;        // 64 MB
    const size_t szAN   = (size_t)NB * PP * DD * 4;        // 4 MB
    const size_t szPART = (size_t)128 * NB * PP * 4;       // 8 MB (128 chunks)
    const size_t szSUMP = (size_t)16 * NB * PP * 4;        // 1 MB (16 tiles)
    const size_t szV    = (size_t)NB * PP * 4;             // 64 KB
    unsigned short* C16 = (unsigned short*)(ws + off); off += szC16;
    float* an    = (float*)(ws + off); off += szAN;
    float* bn    = (float*)(ws + off); off += szAN;
    float* vmp   = (float*)(ws + off); off += szPART;
    float* vsp   = (float*)(ws + off); off += szPART;
    float* rpart = (float*)(ws + off); off += szSUMP;
    float* cpart = (float*)(ws + off); off += szSUMP;
    float* rowS  = (float*)(ws + off); off += szV;
    float* colS  = (float*)(ws + off); off += szV;
    float* elm   = (float*)(ws + off); off += szV;
    float* eln   = (float*)(ws + off); off += szV;
    float* u     = (float*)(ws + off); off += szV;
    float* v     = (float*)(ws + off); off += szV;
    float* du    = (float*)(ws + off); off += szV;
    int*   conv  = (int*)  (ws + off); off += 64;
    if (ws_size < off) return;

    init_kernel<<<64, 256, 0, stream>>>(u, v, conv, out);
    norm_kernel<<<(2 * NB * PP) / 4, 256, 0, stream>>>(a, b, an, bn);
    cost_kernel<<<dim3(PP / 128, PP / 128, NB), 256, 0, stream>>>(an, bn, C16, rpart, cpart);
    sums_combine_kernel<<<64, 256, 0, stream>>>(rpart, cpart, rowS, colS);
    weights_kernel<<<16, 256, 0, stream>>>(rowS, colS, elm, eln);
    for (int it = 0; it < TMAX; ++it) {
        uv_pass<<<NB * 128, 256, 0, stream>>>(C16, v, elm, u, du, vmp, vsp, conv);
        v_combine_err<<<64, 256, 0, stream>>>(vmp, vsp, eln, v, du, conv);
    }
    emd_kernel<<<NB * PP / 4, 256, 0, stream>>>(C16, u, v, out);
}

// Round 5
// 492.340 us; speedup vs baseline: 1.4028x; 1.4028x over previous
//
#include <hip/hip_runtime.h>
#include <math.h>

#define NB 8
#define PP 2048
#define DD 64
#define EPSF 1e-3f
#define RCPE 1000.0f
#define TMAX 10
#define THRESHF 0.1f
#define NEG_INF (-1e30f)
#define QSCALE 32767.5f                 // cost in [0,2] -> u16
#define S_DEQ  (1.0f / 32767.5f)
#define KR 256                          // row candidate cap (4/lane)
#define KC 384                          // col candidate cap (6/lane)
#define TSEL 0.15f                      // selection margin

__device__ __forceinline__ float waveAllMax(float v) {
#pragma unroll
    for (int m = 1; m < 64; m <<= 1) v = fmaxf(v, __shfl_xor(v, m, 64));
    return v;
}
__device__ __forceinline__ float waveAllMin(float v) {
#pragma unroll
    for (int m = 1; m < 64; m <<= 1) v = fminf(v, __shfl_xor(v, m, 64));
    return v;
}
__device__ __forceinline__ float waveAllSum(float v) {
#pragma unroll
    for (int m = 1; m < 64; m <<= 1) v += __shfl_xor(v, m, 64);
    return v;
}

// ---- init: zero u, v, ccnt, conv, out --------------------------------------
__global__ void init_kernel(float* u, float* v, int* ccnt, int* conv, float* out) {
    int t = blockIdx.x * 256 + threadIdx.x;   // 16384 threads
    u[t] = 0.0f; v[t] = 0.0f; ccnt[t] = 0;
    if (t == 0) *conv = 0;
    if (t < NB) out[t] = 0.0f;
}

// ---- L2 normalize: one wave per row ----------------------------------------
__global__ void norm_kernel(const float* __restrict__ a, const float* __restrict__ b,
                            float* __restrict__ an, float* __restrict__ bn) {
    int wave = (blockIdx.x * blockDim.x + threadIdx.x) >> 6;
    int lane = threadIdx.x & 63;
    const float* src; float* dst; int row;
    if (wave < NB * PP) { src = a; dst = an; row = wave; }
    else                { src = b; dst = bn; row = wave - NB * PP; }
    float x = src[(size_t)row * DD + lane];
    float ss = waveAllSum(x * x);
    float r = 1.0f / fmaxf(sqrtf(ss), 1e-12f);
    dst[(size_t)row * DD + lane] = x * r;
}

// ---- cost GEMM: 128x128 tile, 8x8 acc; quant store + sum & min partials ----
// LDS segment swizzle: element i lives at i + 4*(i>>5)  -> 2-way banks (free)
#define CT 140
#define SW(i) ((i) + 4 * ((i) >> 5))
__global__ __launch_bounds__(256) void cost_kernel(const float* __restrict__ an,
        const float* __restrict__ bn, unsigned short* __restrict__ C16,
        float* __restrict__ rpart, float* __restrict__ cpart,
        unsigned* __restrict__ rminp, unsigned* __restrict__ cminp) {
    int b  = blockIdx.z;
    int i0 = blockIdx.y * 128;
    int j0 = blockIdx.x * 128;
    __shared__ float As[64][CT];
    __shared__ float Bs[64][CT];
    __shared__ float cs[16][128];
    int t = threadIdx.x;
    {
        int r  = t >> 1;
        int kh = (t & 1) * 32;
        int rs = SW(r);
        const float4* pa = (const float4*)&an[((size_t)b * PP + i0 + r) * DD + kh];
        const float4* pb = (const float4*)&bn[((size_t)b * PP + j0 + r) * DD + kh];
#pragma unroll
        for (int q = 0; q < 8; ++q) {
            float4 va = pa[q]; float4 vb = pb[q];
            int k = kh + q * 4;
            As[k+0][rs] = va.x; As[k+1][rs] = va.y; As[k+2][rs] = va.z; As[k+3][rs] = va.w;
            Bs[k+0][rs] = vb.x; Bs[k+1][rs] = vb.y; Bs[k+2][rs] = vb.z; Bs[k+3][rs] = vb.w;
        }
    }
    __syncthreads();
    int tx = t & 15, ty = t >> 4;
    int aoff = SW(ty * 8), boff = SW(tx * 8);
    float acc[8][8] = {};
#pragma unroll 4
    for (int k = 0; k < 64; ++k) {
        float4 a0 = *(const float4*)&As[k][aoff];
        float4 a1 = *(const float4*)&As[k][aoff + 4];
        float4 b0 = *(const float4*)&Bs[k][boff];
        float4 b1 = *(const float4*)&Bs[k][boff + 4];
        float aa[8] = {a0.x, a0.y, a0.z, a0.w, a1.x, a1.y, a1.z, a1.w};
        float bb[8] = {b0.x, b0.y, b0.z, b0.w, b1.x, b1.y, b1.z, b1.w};
#pragma unroll
        for (int r = 0; r < 8; ++r)
#pragma unroll
            for (int c = 0; c < 8; ++c)
                acc[r][c] += aa[r] * bb[c];
    }
    // epilogue: quant store + row sum/min partials + col sum/min accumulators
    int lane = t & 63;
    unsigned colmp[8];
    float colsum[8];
#pragma unroll
    for (int c = 0; c < 8; ++c) { colmp[c] = 0xFFFFFFFFu; colsum[c] = 0.0f; }
#pragma unroll
    for (int r = 0; r < 8; ++r) {
        int row = i0 + ty * 8 + r;
        unsigned q[8];
#pragma unroll
        for (int c = 0; c < 8; ++c) {
            float cc = fminf(fmaxf(1.0f - acc[r][c], 0.0f), 2.0f);
            q[c] = __float2uint_rn(cc * QSCALE);
        }
        ushort4 q0, q1;
        q0.x = (unsigned short)q[0]; q0.y = (unsigned short)q[1];
        q0.z = (unsigned short)q[2]; q0.w = (unsigned short)q[3];
        q1.x = (unsigned short)q[4]; q1.y = (unsigned short)q[5];
        q1.z = (unsigned short)q[6]; q1.w = (unsigned short)q[7];
        *(ushort4*)&C16[((size_t)b * PP + row) * PP + j0 + tx * 8]     = q0;
        *(ushort4*)&C16[((size_t)b * PP + row) * PP + j0 + tx * 8 + 4] = q1;
        float rs = acc[r][0] + acc[r][1] + acc[r][2] + acc[r][3]
                 + acc[r][4] + acc[r][5] + acc[r][6] + acc[r][7];
        unsigned rmp = 0xFFFFFFFFu;
#pragma unroll
        for (int c = 0; c < 8; ++c) {
            unsigned p = (q[c] << 16) | (unsigned)(j0 + tx * 8 + c);
            rmp = min(rmp, p);
            colmp[c] = min(colmp[c], (q[c] << 16) | (unsigned)row);
            colsum[c] += acc[r][c];
        }
#pragma unroll
        for (int m = 1; m < 16; m <<= 1) {
            rs += __shfl_xor(rs, m, 64);
            rmp = min(rmp, (unsigned)__shfl_xor((int)rmp, m, 64));
        }
        if ((lane & 15) == 0) {
            rpart[(size_t)blockIdx.x * (NB * PP) + b * PP + row] = rs;
            rminp[(size_t)blockIdx.x * (NB * PP) + b * PP + row] = rmp;
        }
    }
#pragma unroll
    for (int c = 0; c < 8; ++c) cs[ty][tx * 8 + c] = colsum[c];
    __syncthreads();
    if (t < 128) {
        float tot = 0.0f;
#pragma unroll
        for (int g = 0; g < 16; ++g) tot += cs[g][t];
        cpart[(size_t)blockIdx.y * (NB * PP) + b * PP + j0 + t] = tot;
    }
    __syncthreads();
    unsigned* csu = (unsigned*)cs;
#pragma unroll
    for (int c = 0; c < 8; ++c) csu[ty * 128 + tx * 8 + c] = colmp[c];
    __syncthreads();
    if (t < 128) {
        unsigned mn = 0xFFFFFFFFu;
#pragma unroll
        for (int g = 0; g < 16; ++g) mn = min(mn, csu[g * 128 + t]);
        cminp[(size_t)blockIdx.y * (NB * PP) + b * PP + j0 + t] = mn;
    }
}

// ---- combine partials -> rowS, colS, rowminp, colminp ----------------------
__global__ void combine_kernel(const float* __restrict__ rpart, const float* __restrict__ cpart,
                               const unsigned* __restrict__ rminp, const unsigned* __restrict__ cminp,
                               float* __restrict__ rowS, float* __restrict__ colS,
                               unsigned* __restrict__ rowminp, unsigned* __restrict__ colminp) {
    int idx = blockIdx.x * 256 + threadIdx.x;   // 64 blocks -> 16384
    float rs = 0.0f, csf = 0.0f;
    unsigned rm = 0xFFFFFFFFu, cm = 0xFFFFFFFFu;
#pragma unroll
    for (int k = 0; k < 16; ++k) {
        rs  += rpart[(size_t)k * (NB * PP) + idx];
        csf += cpart[(size_t)k * (NB * PP) + idx];
        rm = min(rm, rminp[(size_t)k * (NB * PP) + idx]);
        cm = min(cm, cminp[(size_t)k * (NB * PP) + idx]);
    }
    rowS[idx] = rs; colS[idx] = csf;
    rowminp[idx] = rm; colminp[idx] = cm;
}

// ---- weights + selection thresholds ----------------------------------------
__device__ __forceinline__ float blockReduceSum256(float v, float* sh) {
    v = waveAllSum(v);
    int lane = threadIdx.x & 63, w = threadIdx.x >> 6;
    if (lane == 0) sh[w] = v;
    __syncthreads();
    float r = sh[0] + sh[1] + sh[2] + sh[3];
    __syncthreads();
    return r;
}

__global__ void weights_kernel(const float* __restrict__ rowS, const float* __restrict__ colS,
                               const unsigned* __restrict__ rowminp, const unsigned* __restrict__ colminp,
                               float* __restrict__ elm, float* __restrict__ eln,
                               float* __restrict__ colminf, float* __restrict__ cthresh) {
    __shared__ float sh[4];
    int b = blockIdx.x & 7;
    bool isB = blockIdx.x >= 8;
    const float* src = (isB ? colS : rowS) + b * PP;
    float* dst = (isB ? eln : elm) + b * PP;
    int tid = threadIdx.x;
    float x[8];
    float sabs = 0.0f;
#pragma unroll
    for (int q = 0; q < 8; ++q) {
        x[q] = src[tid + q * 256] * (1.0f / (float)PP);
        sabs += fabsf(x[q]);
    }
    sabs = blockReduceSum256(sabs, sh);
    float inv1 = 1.0f / fmaxf(sabs, 1e-12f);
    float spos = 0.0f;
#pragma unroll
    for (int q = 0; q < 8; ++q) {
        x[q] = fmaxf(x[q] * inv1, 0.0f);
        spos += x[q];
    }
    spos = blockReduceSum256(spos, sh);
    float inv2 = 1.0f / fmaxf(spos, 1e-12f);
#pragma unroll
    for (int q = 0; q < 8; ++q)
        dst[tid + q * 256] = EPSF * logf(x[q] * inv2 + 1e-8f);
    if (isB) {
        // per-column: colminf, cthresh = (colmin - rowmin[argmin_row]) + T
#pragma unroll
        for (int q = 0; q < 8; ++q) {
            int idx = b * PP + tid + q * 256;
            unsigned pc = colminp[idx];
            unsigned arg = pc & 0xffffu;
            unsigned pr = rowminp[b * PP + arg];
            float cmf = (float)(pc >> 16) * S_DEQ;
            colminf[idx] = cmf;
            cthresh[idx] = cmf - (float)(pr >> 16) * S_DEQ + TSEL;
        }
    }
}

// ---- candidate selection: one pass over C16 (row lists + col pushes) -------
__global__ __launch_bounds__(256) void row_select(const unsigned short* __restrict__ C16,
        const float* __restrict__ colminf, const float* __restrict__ cthresh,
        unsigned* __restrict__ rlist, int* __restrict__ rcnt,
        unsigned* __restrict__ clist, int* __restrict__ ccnt) {
    int w = threadIdx.x >> 6, lane = threadIdx.x & 63;
    int row = blockIdx.x * 4 + w;           // global row 0..16383
    int b = row >> 11, i = row & (PP - 1);
    const uint4* cp = (const uint4*)(C16 + (size_t)row * PP);
    uint4 q4[4];
#pragma unroll
    for (int g = 0; g < 4; ++g) q4[g] = cp[g * 64 + lane];
    const float* cmb = colminf + b * PP;
    const float* ctb = cthresh + b * PP;
    // pass A: row min cost and min reduced cost
    float rmin = 1e30f, rpmin = 1e30f;
#pragma unroll
    for (int g = 0; g < 4; ++g) {
        int jb = g * 512 + lane * 8;
        float4 cm0 = *(const float4*)(cmb + jb);
        float4 cm1 = *(const float4*)(cmb + jb + 4);
        float cm[8] = {cm0.x, cm0.y, cm0.z, cm0.w, cm1.x, cm1.y, cm1.z, cm1.w};
        unsigned qq[4] = {q4[g].x, q4[g].y, q4[g].z, q4[g].w};
#pragma unroll
        for (int h = 0; h < 4; ++h) {
            float c0 = (float)(qq[h] & 0xffffu) * S_DEQ;
            float c1 = (float)(qq[h] >> 16) * S_DEQ;
            rmin = fminf(rmin, fminf(c0, c1));
            rpmin = fminf(rpmin, fminf(c0 - cm[h * 2], c1 - cm[h * 2 + 1]));
        }
    }
    rmin = waveAllMin(rmin);
    float rth = waveAllMin(rpmin) + TSEL;
    // pass B: emit row candidates (ballot compaction) + col pushes (atomics)
    int base = 0;
#pragma unroll
    for (int g = 0; g < 4; ++g) {
        int jb = g * 512 + lane * 8;
        float4 cm0 = *(const float4*)(cmb + jb);
        float4 cm1 = *(const float4*)(cmb + jb + 4);
        float4 ct0 = *(const float4*)(ctb + jb);
        float4 ct1 = *(const float4*)(ctb + jb + 4);
        float cm[8] = {cm0.x, cm0.y, cm0.z, cm0.w, cm1.x, cm1.y, cm1.z, cm1.w};
        float ct[8] = {ct0.x, ct0.y, ct0.z, ct0.w, ct1.x, ct1.y, ct1.z, ct1.w};
        unsigned qq[4] = {q4[g].x, q4[g].y, q4[g].z, q4[g].w};
#pragma unroll
        for (int e = 0; e < 8; ++e) {
            unsigned q = (qq[e >> 1] >> ((e & 1) * 16)) & 0xffffu;
            float cf = (float)q * S_DEQ;
            int j = jb + e;
            bool rq = (cf - cm[e]) <= rth;
            unsigned long long mb = __ballot(rq);
            if (rq) {
                int pos = base + __popcll(mb & ((1ull << lane) - 1ull));
                if (pos < KR) rlist[(size_t)row * KR + pos] = ((unsigned)j << 16) | q;
            }
            base += __popcll(mb);
            bool cq = (cf - rmin) <= ct[e];
            if (cq) {
                int idx = atomicAdd(&ccnt[b * PP + j], 1);
                if (idx < KC) clist[(size_t)(b * PP + j) * KC + idx] = ((unsigned)i << 16) | q;
            }
        }
    }
    if (lane == 0) rcnt[row] = base;
}

// ---- Sinkhorn u-update over row candidates ---------------------------------
__global__ __launch_bounds__(256) void u_kernel(const unsigned* __restrict__ rlist,
        const int* __restrict__ rcnt, const float* __restrict__ v,
        const float* __restrict__ elm, float* __restrict__ u, float* __restrict__ du,
        const int* __restrict__ conv) {
    if (*conv) return;
    int w = threadIdx.x >> 6, lane = threadIdx.x & 63;
    int row = blockIdx.x * 4 + w;
    int b = row >> 11;
    int cnt = min(rcnt[row], KR);
    const unsigned* lst = rlist + (size_t)row * KR;
    const float* vb = v + b * PP;
    float x[4] = {NEG_INF, NEG_INF, NEG_INF, NEG_INF};
#pragma unroll
    for (int s = 0; s < 4; ++s) {
        int e = lane + s * 64;
        if (e < cnt) {
            unsigned wrd = lst[e];
            x[s] = vb[wrd >> 16] - (float)(wrd & 0xffffu) * S_DEQ;
        }
    }
    float m = fmaxf(fmaxf(x[0], x[1]), fmaxf(x[2], x[3]));
    m = waveAllMax(m);
    float s = __expf((x[0] - m) * RCPE) + __expf((x[1] - m) * RCPE)
            + __expf((x[2] - m) * RCPE) + __expf((x[3] - m) * RCPE);
    s = waveAllSum(s);
    if (lane == 0) {
        float unew = elm[row] - m - EPSF * logf(s);
        du[row] = fabsf(unew - u[row]);
        u[row] = unew;
    }
}

// ---- Sinkhorn v-update over col candidates (+ err/conv in block 0) ---------
__global__ __launch_bounds__(256) void v_kernel(const unsigned* __restrict__ clist,
        const int* __restrict__ ccnt, const float* __restrict__ u,
        const float* __restrict__ eln, float* __restrict__ v,
        const float* __restrict__ du, int* __restrict__ conv) {
    if (*conv) return;
    int w = threadIdx.x >> 6, lane = threadIdx.x & 63;
    int jg = blockIdx.x * 4 + w;
    int b = jg >> 11;
    int cnt = min(ccnt[jg], KC);
    const unsigned* lst = clist + (size_t)jg * KC;
    const float* ub = u + b * PP;
    float x[6] = {NEG_INF, NEG_INF, NEG_INF, NEG_INF, NEG_INF, NEG_INF};
#pragma unroll
    for (int s = 0; s < 6; ++s) {
        int e = lane + s * 64;
        if (e < cnt) {
            unsigned wrd = lst[e];
            x[s] = ub[wrd >> 16] - (float)(wrd & 0xffffu) * S_DEQ;
        }
    }
    float m = NEG_INF;
#pragma unroll
    for (int s = 0; s < 6; ++s) m = fmaxf(m, x[s]);
    m = waveAllMax(m);
    float s = 0.0f;
#pragma unroll
    for (int k = 0; k < 6; ++k) s += __expf((x[k] - m) * RCPE);
    s = waveAllSum(s);
    if (lane == 0)
        v[jg] = eln[jg] - m - EPSF * logf(s);
    // err reduce + conv (du written by this iteration's u_kernel)
    if (blockIdx.x == 0) {
        __shared__ float sh[4];
        int t = threadIdx.x;
        float sacc = 0.0f;
#pragma unroll
        for (int q = 0; q < 64; ++q) sacc += du[t + q * 256];
        sacc = waveAllSum(sacc);
        if ((t & 63) == 0) sh[t >> 6] = sacc;
        __syncthreads();
        if (t == 0) {
            float tot = sh[0] + sh[1] + sh[2] + sh[3];
            if (tot * (1.0f / (float)NB) < THRESHF) *conv = 1;
        }
    }
}

// ---- final: D[b] = sum over row candidates of exp((u+v-C)/eps)*C -----------
__global__ __launch_bounds__(256) void emd_kernel(const unsigned* __restrict__ rlist,
        const int* __restrict__ rcnt, const float* __restrict__ u,
        const float* __restrict__ v, float* __restrict__ out) {
    __shared__ float sh[4];
    int w = threadIdx.x >> 6, lane = threadIdx.x & 63;
    int row = blockIdx.x * 4 + w;
    int b = row >> 11;
    int cnt = min(rcnt[row], KR);
    const unsigned* lst = rlist + (size_t)row * KR;
    const float* vb = v + b * PP;
    float ui = u[row];
    float s = 0.0f;
#pragma unroll
    for (int k = 0; k < 4; ++k) {
        int e = lane + k * 64;
        if (e < cnt) {
            unsigned wrd = lst[e];
            float cf = (float)(wrd & 0xffffu) * S_DEQ;
            s += __expf((ui + vb[wrd >> 16] - cf) * RCPE) * cf;
        }
    }
    s = waveAllSum(s);
    if (lane == 0) sh[w] = s;
    __syncthreads();
    if (threadIdx.x == 0) atomicAdd(&out[b], sh[0] + sh[1] + sh[2] + sh[3]);
}

extern "C" void kernel_launch(void* const* d_in, const int* in_sizes, int n_in,
                              void* d_out, int out_size, void* d_ws, size_t ws_size,
                              hipStream_t stream) {
    const float* a = (const float*)d_in[0];
    const float* b = (const float*)d_in[1];
    float* out = (float*)d_out;

    char* ws = (char*)d_ws;
    size_t off = 0;
    const size_t szC16 = (size_t)NB * PP * PP * 2;          // 64 MB
    const size_t szAN  = (size_t)NB * PP * DD * 4;          // 4 MB
    const size_t szRL  = (size_t)NB * PP * KR * 4;          // 16 MB
    const size_t szCL  = (size_t)NB * PP * KC * 4;          // 24 MB
    const size_t szP   = (size_t)16 * NB * PP * 4;          // 1 MB
    const size_t szV   = (size_t)NB * PP * 4;               // 64 KB
    unsigned short* C16 = (unsigned short*)(ws + off); off += szC16;
    float* an    = (float*)(ws + off); off += szAN;
    float* bn    = (float*)(ws + off); off += szAN;
    unsigned* rlist = (unsigned*)(ws + off); off += szRL;
    unsigned* clist = (unsigned*)(ws + off); off += szCL;
    float* rpart = (float*)(ws + off); off += szP;
    float* cpart = (float*)(ws + off); off += szP;
    unsigned* rminp = (unsigned*)(ws + off); off += szP;
    unsigned* cminp = (unsigned*)(ws + off); off += szP;
    float* rowS  = (float*)(ws + off); off += szV;
    float* colS  = (float*)(ws + off); off += szV;
    unsigned* rowminp = (unsigned*)(ws + off); off += szV;
    unsigned* colminp = (unsigned*)(ws + off); off += szV;
    float* colminf = (float*)(ws + off); off += szV;
    float* cthresh = (float*)(ws + off); off += szV;
    float* elm   = (float*)(ws + off); off += szV;
    float* eln   = (float*)(ws + off); off += szV;
    float* u     = (float*)(ws + off); off += szV;
    float* v     = (float*)(ws + off); off += szV;
    float* du    = (float*)(ws + off); off += szV;
    int* rcnt    = (int*)(ws + off); off += szV;
    int* ccnt    = (int*)(ws + off); off += szV;
    int* conv    = (int*)(ws + off); off += 64;
    if (ws_size < off) return;

    init_kernel<<<64, 256, 0, stream>>>(u, v, ccnt, conv, out);
    norm_kernel<<<(2 * NB * PP) / 4, 256, 0, stream>>>(a, b, an, bn);
    cost_kernel<<<dim3(PP / 128, PP / 128, NB), 256, 0, stream>>>(an, bn, C16,
            rpart, cpart, rminp, cminp);
    combine_kernel<<<64, 256, 0, stream>>>(rpart, cpart, rminp, cminp,
            rowS, colS, rowminp, colminp);
    weights_kernel<<<16, 256, 0, stream>>>(rowS, colS, rowminp, colminp,
            elm, eln, colminf, cthresh);
    row_select<<<NB * PP / 4, 256, 0, stream>>>(C16, colminf, cthresh,
            rlist, rcnt, clist, ccnt);
    for (int it = 0; it < TMAX; ++it) {
        u_kernel<<<NB * PP / 4, 256, 0, stream>>>(rlist, rcnt, v, elm, u, du, conv);
        v_kernel<<<NB * PP / 4, 256, 0, stream>>>(clist, ccnt, u, eln, v, du, conv);
    }
    emd_kernel<<<NB * PP / 4, 256, 0, stream>>>(rlist, rcnt, u, v, out);
}

// Round 7
// 433.155 us; speedup vs baseline: 1.5945x; 1.1366x over previous
//
#include <hip/hip_runtime.h>
#include <math.h>

#define NB 8
#define PP 2048
#define DD 64
#define EPSF 1e-3f
#define RCPE 1000.0f
#define TMAX 10
#define THRESHF 0.1f
#define NEG_INF (-1e30f)
#define QSCALE 32767.5f                 // cost in [0,2] -> u16
#define S_DEQ  (1.0f / 32767.5f)
#define KR 512                          // row candidate cap (8/lane)
#define KC 512                          // col candidate cap (4 segs x 128)
#define TSEL 0.15f                      // selection margin (round-5 proven)

__device__ __forceinline__ float waveAllMax(float v) {
#pragma unroll
    for (int m = 1; m < 64; m <<= 1) v = fmaxf(v, __shfl_xor(v, m, 64));
    return v;
}
__device__ __forceinline__ float waveAllMin(float v) {
#pragma unroll
    for (int m = 1; m < 64; m <<= 1) v = fminf(v, __shfl_xor(v, m, 64));
    return v;
}
__device__ __forceinline__ float waveAllSum(float v) {
#pragma unroll
    for (int m = 1; m < 64; m <<= 1) v += __shfl_xor(v, m, 64);
    return v;
}

// ---- init ------------------------------------------------------------------
__global__ void init_kernel(float* u, float* v, int* conv, float* out) {
    int t = blockIdx.x * 256 + threadIdx.x;   // 16384 threads
    u[t] = 0.0f; v[t] = 0.0f;
    if (t == 0) *conv = 0;
    if (t < NB) out[t] = 0.0f;
}

// ---- L2 normalize: one wave per row ----------------------------------------
__global__ void norm_kernel(const float* __restrict__ a, const float* __restrict__ b,
                            float* __restrict__ an, float* __restrict__ bn) {
    int wave = (blockIdx.x * blockDim.x + threadIdx.x) >> 6;
    int lane = threadIdx.x & 63;
    const float* src; float* dst; int row;
    if (wave < NB * PP) { src = a; dst = an; row = wave; }
    else                { src = b; dst = bn; row = wave - NB * PP; }
    float x = src[(size_t)row * DD + lane];
    float ss = waveAllSum(x * x);
    float r = 1.0f / fmaxf(sqrtf(ss), 1e-12f);
    dst[(size_t)row * DD + lane] = x * r;
}

// ---- cost GEMM: 128x128 tile, 8x8 acc; quant store + sum & min partials ----
#define CT 140
#define SW(i) ((i) + 4 * ((i) >> 5))
__global__ __launch_bounds__(256) void cost_kernel(const float* __restrict__ an,
        const float* __restrict__ bn, unsigned short* __restrict__ C16,
        float* __restrict__ rpart, float* __restrict__ cpart,
        unsigned* __restrict__ rminp, unsigned* __restrict__ cminp) {
    int b  = blockIdx.z;
    int i0 = blockIdx.y * 128;
    int j0 = blockIdx.x * 128;
    __shared__ float As[64][CT];
    __shared__ float Bs[64][CT];
    __shared__ float cs[16][128];
    int t = threadIdx.x;
    {
        int r  = t >> 1;
        int kh = (t & 1) * 32;
        int rs = SW(r);
        const float4* pa = (const float4*)&an[((size_t)b * PP + i0 + r) * DD + kh];
        const float4* pb = (const float4*)&bn[((size_t)b * PP + j0 + r) * DD + kh];
#pragma unroll
        for (int q = 0; q < 8; ++q) {
            float4 va = pa[q]; float4 vb = pb[q];
            int k = kh + q * 4;
            As[k+0][rs] = va.x; As[k+1][rs] = va.y; As[k+2][rs] = va.z; As[k+3][rs] = va.w;
            Bs[k+0][rs] = vb.x; Bs[k+1][rs] = vb.y; Bs[k+2][rs] = vb.z; Bs[k+3][rs] = vb.w;
        }
    }
    __syncthreads();
    int tx = t & 15, ty = t >> 4;
    int aoff = SW(ty * 8), boff = SW(tx * 8);
    float acc[8][8] = {};
#pragma unroll 4
    for (int k = 0; k < 64; ++k) {
        float4 a0 = *(const float4*)&As[k][aoff];
        float4 a1 = *(const float4*)&As[k][aoff + 4];
        float4 b0 = *(const float4*)&Bs[k][boff];
        float4 b1 = *(const float4*)&Bs[k][boff + 4];
        float aa[8] = {a0.x, a0.y, a0.z, a0.w, a1.x, a1.y, a1.z, a1.w};
        float bb[8] = {b0.x, b0.y, b0.z, b0.w, b1.x, b1.y, b1.z, b1.w};
#pragma unroll
        for (int r = 0; r < 8; ++r)
#pragma unroll
            for (int c = 0; c < 8; ++c)
                acc[r][c] += aa[r] * bb[c];
    }
    int lane = t & 63;
    unsigned colmp[8];
    float colsum[8];
#pragma unroll
    for (int c = 0; c < 8; ++c) { colmp[c] = 0xFFFFFFFFu; colsum[c] = 0.0f; }
#pragma unroll
    for (int r = 0; r < 8; ++r) {
        int row = i0 + ty * 8 + r;
        unsigned q[8];
#pragma unroll
        for (int c = 0; c < 8; ++c) {
            float cc = fminf(fmaxf(1.0f - acc[r][c], 0.0f), 2.0f);
            q[c] = __float2uint_rn(cc * QSCALE);
        }
        ushort4 q0, q1;
        q0.x = (unsigned short)q[0]; q0.y = (unsigned short)q[1];
        q0.z = (unsigned short)q[2]; q0.w = (unsigned short)q[3];
        q1.x = (unsigned short)q[4]; q1.y = (unsigned short)q[5];
        q1.z = (unsigned short)q[6]; q1.w = (unsigned short)q[7];
        *(ushort4*)&C16[((size_t)b * PP + row) * PP + j0 + tx * 8]     = q0;
        *(ushort4*)&C16[((size_t)b * PP + row) * PP + j0 + tx * 8 + 4] = q1;
        float rs = acc[r][0] + acc[r][1] + acc[r][2] + acc[r][3]
                 + acc[r][4] + acc[r][5] + acc[r][6] + acc[r][7];
        unsigned rmp = 0xFFFFFFFFu;
#pragma unroll
        for (int c = 0; c < 8; ++c) {
            rmp = min(rmp, (q[c] << 16) | (unsigned)(j0 + tx * 8 + c));
            colmp[c] = min(colmp[c], (q[c] << 16) | (unsigned)row);
            colsum[c] += acc[r][c];
        }
#pragma unroll
        for (int m = 1; m < 16; m <<= 1) {
            rs += __shfl_xor(rs, m, 64);
            rmp = min(rmp, (unsigned)__shfl_xor((int)rmp, m, 64));
        }
        if ((lane & 15) == 0) {
            rpart[(size_t)blockIdx.x * (NB * PP) + b * PP + row] = rs;
            rminp[(size_t)blockIdx.x * (NB * PP) + b * PP + row] = rmp;
        }
    }
#pragma unroll
    for (int c = 0; c < 8; ++c) cs[ty][tx * 8 + c] = colsum[c];
    __syncthreads();
    if (t < 128) {
        float tot = 0.0f;
#pragma unroll
        for (int g = 0; g < 16; ++g) tot += cs[g][t];
        cpart[(size_t)blockIdx.y * (NB * PP) + b * PP + j0 + t] = tot;
    }
    __syncthreads();
    unsigned* csu = (unsigned*)cs;
#pragma unroll
    for (int c = 0; c < 8; ++c) csu[ty * 128 + tx * 8 + c] = colmp[c];
    __syncthreads();
    if (t < 128) {
        unsigned mn = 0xFFFFFFFFu;
#pragma unroll
        for (int g = 0; g < 16; ++g) mn = min(mn, csu[g * 128 + t]);
        cminp[(size_t)blockIdx.y * (NB * PP) + b * PP + j0 + t] = mn;
    }
}

// ---- combine partials ------------------------------------------------------
__global__ void combine_kernel(const float* __restrict__ rpart, const float* __restrict__ cpart,
                               const unsigned* __restrict__ rminp, const unsigned* __restrict__ cminp,
                               float* __restrict__ rowS, float* __restrict__ colS,
                               unsigned* __restrict__ rowminp, unsigned* __restrict__ colminp) {
    int idx = blockIdx.x * 256 + threadIdx.x;
    float rs = 0.0f, csf = 0.0f;
    unsigned rm = 0xFFFFFFFFu, cm = 0xFFFFFFFFu;
#pragma unroll
    for (int k = 0; k < 16; ++k) {
        rs  += rpart[(size_t)k * (NB * PP) + idx];
        csf += cpart[(size_t)k * (NB * PP) + idx];
        rm = min(rm, rminp[(size_t)k * (NB * PP) + idx]);
        cm = min(cm, cminp[(size_t)k * (NB * PP) + idx]);
    }
    rowS[idx] = rs; colS[idx] = csf;
    rowminp[idx] = rm; colminp[idx] = cm;
}

// ---- weights + thresholds --------------------------------------------------
__device__ __forceinline__ float blockReduceSum256(float v, float* sh) {
    v = waveAllSum(v);
    int lane = threadIdx.x & 63, w = threadIdx.x >> 6;
    if (lane == 0) sh[w] = v;
    __syncthreads();
    float r = sh[0] + sh[1] + sh[2] + sh[3];
    __syncthreads();
    return r;
}

__global__ void weights_kernel(const float* __restrict__ rowS, const float* __restrict__ colS,
                               const unsigned* __restrict__ rowminp, const unsigned* __restrict__ colminp,
                               float* __restrict__ elm, float* __restrict__ eln,
                               float* __restrict__ rowminf, float* __restrict__ colminf,
                               float* __restrict__ cthresh) {
    __shared__ float sh[4];
    int b = blockIdx.x & 7;
    bool isB = blockIdx.x >= 8;
    const float* src = (isB ? colS : rowS) + b * PP;
    float* dst = (isB ? eln : elm) + b * PP;
    int tid = threadIdx.x;
    float x[8];
    float sabs = 0.0f;
#pragma unroll
    for (int q = 0; q < 8; ++q) {
        x[q] = src[tid + q * 256] * (1.0f / (float)PP);
        sabs += fabsf(x[q]);
    }
    sabs = blockReduceSum256(sabs, sh);
    float inv1 = 1.0f / fmaxf(sabs, 1e-12f);
    float spos = 0.0f;
#pragma unroll
    for (int q = 0; q < 8; ++q) {
        x[q] = fmaxf(x[q] * inv1, 0.0f);
        spos += x[q];
    }
    spos = blockReduceSum256(spos, sh);
    float inv2 = 1.0f / fmaxf(spos, 1e-12f);
#pragma unroll
    for (int q = 0; q < 8; ++q)
        dst[tid + q * 256] = EPSF * logf(x[q] * inv2 + 1e-8f);
    if (isB) {
#pragma unroll
        for (int q = 0; q < 8; ++q) {
            int idx = b * PP + tid + q * 256;
            unsigned pc = colminp[idx];
            unsigned arg = pc & 0xffffu;
            unsigned pr = rowminp[b * PP + arg];
            float cmf = (float)(pc >> 16) * S_DEQ;
            colminf[idx] = cmf;
            cthresh[idx] = cmf - (float)(pr >> 16) * S_DEQ + TSEL;
        }
    } else {
#pragma unroll
        for (int q = 0; q < 8; ++q) {
            int idx = b * PP + tid + q * 256;
            rowminf[idx] = (float)(rowminp[idx] >> 16) * S_DEQ;
        }
    }
}

// ---- row candidate selection: wave per row, ballot compaction, no atomics --
__global__ __launch_bounds__(256) void row_select(const unsigned short* __restrict__ C16,
        const float* __restrict__ colminf,
        unsigned* __restrict__ rlist, int* __restrict__ rcnt) {
    int w = threadIdx.x >> 6, lane = threadIdx.x & 63;
    int row = blockIdx.x * 4 + w;
    int b = row >> 11;
    const uint4* cp = (const uint4*)(C16 + (size_t)row * PP);
    uint4 q4[4];
#pragma unroll
    for (int g = 0; g < 4; ++g) q4[g] = cp[g * 64 + lane];
    const float* cmb = colminf + b * PP;
    float rpmin = 1e30f;
#pragma unroll
    for (int g = 0; g < 4; ++g) {
        int jb = g * 512 + lane * 8;
        float4 cm0 = *(const float4*)(cmb + jb);
        float4 cm1 = *(const float4*)(cmb + jb + 4);
        float cm[8] = {cm0.x, cm0.y, cm0.z, cm0.w, cm1.x, cm1.y, cm1.z, cm1.w};
        unsigned qq[4] = {q4[g].x, q4[g].y, q4[g].z, q4[g].w};
#pragma unroll
        for (int h = 0; h < 4; ++h) {
            float c0 = (float)(qq[h] & 0xffffu) * S_DEQ;
            float c1 = (float)(qq[h] >> 16) * S_DEQ;
            rpmin = fminf(rpmin, fminf(c0 - cm[h * 2], c1 - cm[h * 2 + 1]));
        }
    }
    float rth = waveAllMin(rpmin) + TSEL;
    int base = 0;
#pragma unroll
    for (int g = 0; g < 4; ++g) {
        int jb = g * 512 + lane * 8;
        float4 cm0 = *(const float4*)(cmb + jb);
        float4 cm1 = *(const float4*)(cmb + jb + 4);
        float cm[8] = {cm0.x, cm0.y, cm0.z, cm0.w, cm1.x, cm1.y, cm1.z, cm1.w};
        unsigned qq[4] = {q4[g].x, q4[g].y, q4[g].z, q4[g].w};
#pragma unroll
        for (int e = 0; e < 8; ++e) {
            unsigned q = (qq[e >> 1] >> ((e & 1) * 16)) & 0xffffu;
            float cf = (float)q * S_DEQ;
            bool rq = (cf - cm[e]) <= rth;
            unsigned long long mb = __ballot(rq);
            if (rq) {
                int pos = base + __popcll(mb & ((1ull << lane) - 1ull));
                if (pos < KR) rlist[(size_t)row * KR + pos] = ((unsigned)(jb + e) << 16) | q;
            }
            base += __popcll(mb);
        }
    }
    if (lane == 0) rcnt[row] = base;
}

// ---- col candidate selection: 64-col slab, LDS transpose, no atomics -------
__global__ __launch_bounds__(256) void col_select(const unsigned short* __restrict__ C16,
        const float* __restrict__ rowminf, const float* __restrict__ cthresh,
        unsigned* __restrict__ clist, int* __restrict__ scnt) {
    int b = blockIdx.y;
    int j0 = blockIdx.x * 64;
    int t = threadIdx.x;
    int col = t & 63, seg = t >> 6;
    __shared__ unsigned tile32[64][36];   // 64 rows x 32 u32 (2 cols each), pad->36
    __shared__ float rm_s[64];
    float ctj = cthresh[b * PP + j0 + col];
    int cnt = 0;
    unsigned* mylist = clist + ((size_t)(b * PP + j0 + col)) * KC + seg * 128;
    int lrow = t >> 3, lcc = t & 7;
    uint4 pf0, pf1; float pfr = 0.0f;
    {
        const unsigned short* base0 = C16 + ((size_t)b * PP + lrow) * PP + j0;
        pf0 = ((const uint4*)base0)[lcc];
        pf1 = ((const uint4*)(base0 + (size_t)32 * PP))[lcc];
        if (t < 64) pfr = rowminf[b * PP + t];
    }
    for (int chunk = 0; chunk < 32; ++chunk) {
        *(uint4*)&tile32[lrow][lcc * 4]      = pf0;
        *(uint4*)&tile32[32 + lrow][lcc * 4] = pf1;
        if (t < 64) rm_s[t] = pfr;
        __syncthreads();
        if (chunk < 31) {
            int r0n = (chunk + 1) * 64;
            const unsigned short* base0 = C16 + ((size_t)b * PP + r0n + lrow) * PP + j0;
            pf0 = ((const uint4*)base0)[lcc];
            pf1 = ((const uint4*)(base0 + (size_t)32 * PP))[lcc];
            if (t < 64) pfr = rowminf[b * PP + r0n + t];
        }
        int r0 = chunk * 64;
#pragma unroll
        for (int rr = 0; rr < 16; ++rr) {
            int row = seg * 16 + rr;
            unsigned w32 = tile32[row][col >> 1];
            unsigned q = (col & 1) ? (w32 >> 16) : (w32 & 0xffffu);
            float cf = (float)q * S_DEQ;
            if (cf - rm_s[row] <= ctj) {
                if (cnt < 128) mylist[cnt] = ((unsigned)(r0 + row) << 16) | q;
                ++cnt;
            }
        }
        __syncthreads();
    }
    scnt[(b * PP + j0 + col) * 4 + seg] = min(cnt, 128);
}

// ---- Sinkhorn u-update over row candidates (wave per row) ------------------
__global__ __launch_bounds__(256) void u_kernel(const unsigned* __restrict__ rlist,
        const int* __restrict__ rcnt, const float* __restrict__ v,
        const float* __restrict__ elm, float* __restrict__ u, float* __restrict__ du,
        const int* __restrict__ conv) {
    if (*conv) return;
    int w = threadIdx.x >> 6, lane = threadIdx.x & 63;
    int row = blockIdx.x * 4 + w;
    int b = row >> 11;
    int cnt = min(rcnt[row], KR);
    const unsigned* lst = rlist + (size_t)row * KR;
    const float* vb = v + (b << 11);
    float x[8];
    float m = NEG_INF;
#pragma unroll
    for (int s = 0; s < 8; ++s) {
        int e = lane + s * 64;
        x[s] = NEG_INF;
        if (e < cnt) {
            unsigned wd = lst[e];
            x[s] = vb[wd >> 16] - (float)(wd & 0xffffu) * S_DEQ;
        }
        m = fmaxf(m, x[s]);
    }
    m = waveAllMax(m);
    float s = 0.0f;
#pragma unroll
    for (int k = 0; k < 8; ++k) s += __expf((x[k] - m) * RCPE);
    s = waveAllSum(s);
    if (lane == 0) {
        float un = elm[row] - m - EPSF * logf(s);
        du[row] = fabsf(un - u[row]);
        u[row] = un;
    }
}

// ---- Sinkhorn v-update over col candidates (+ err/conv in block 0) ---------
__global__ __launch_bounds__(256) void v_kernel(const unsigned* __restrict__ clist,
        const int* __restrict__ scnt, const float* __restrict__ u,
        const float* __restrict__ eln, float* __restrict__ v,
        const float* __restrict__ du, int* __restrict__ conv) {
    if (*conv) return;
    int w = threadIdx.x >> 6, lane = threadIdx.x & 63;
    int jg = blockIdx.x * 4 + w;
    int b = jg >> 11;
    int4 sc = *(const int4*)&scnt[jg * 4];
    int cn[4] = {sc.x, sc.y, sc.z, sc.w};
    const unsigned* lst = clist + (size_t)jg * KC;
    const float* ub = u + (b << 11);
    float x[8];
    float m = NEG_INF;
#pragma unroll
    for (int s = 0; s < 8; ++s) {
        int e = lane + s * 64;
        int sg = e >> 7, k = e & 127;
        x[s] = NEG_INF;
        if (k < cn[sg]) {
            unsigned wd = lst[sg * 128 + k];
            x[s] = ub[wd >> 16] - (float)(wd & 0xffffu) * S_DEQ;
        }
        m = fmaxf(m, x[s]);
    }
    m = waveAllMax(m);
    float s = 0.0f;
#pragma unroll
    for (int k = 0; k < 8; ++k) s += __expf((x[k] - m) * RCPE);
    s = waveAllSum(s);
    if (lane == 0)
        v[jg] = eln[jg] - m - EPSF * logf(s);
    if (blockIdx.x == 0) {
        __shared__ float sh[4];
        int t = threadIdx.x;
        float sacc = 0.0f;
#pragma unroll
        for (int q = 0; q < 64; ++q) sacc += du[t + q * 256];
        sacc = waveAllSum(sacc);
        if (lane == 0) sh[w] = sacc;
        __syncthreads();
        if (t == 0) {
            float tot = sh[0] + sh[1] + sh[2] + sh[3];
            if (tot * (1.0f / (float)NB) < THRESHF) *conv = 1;
        }
    }
}

// ---- final: D[b] = sum over row candidates of exp((u+v-C)/eps)*C -----------
__global__ __launch_bounds__(256) void emd_kernel(const unsigned* __restrict__ rlist,
        const int* __restrict__ rcnt, const float* __restrict__ u,
        const float* __restrict__ v, float* __restrict__ out) {
    __shared__ float sh[4];
    int w = threadIdx.x >> 6, lane = threadIdx.x & 63;
    int row = blockIdx.x * 4 + w;
    int b = row >> 11;
    int cnt = min(rcnt[row], KR);
    const unsigned* lst = rlist + (size_t)row * KR;
    const float* vb = v + (b << 11);
    float ui = u[row];
    float s = 0.0f;
#pragma unroll
    for (int k = 0; k < 8; ++k) {
        int e = lane + k * 64;
        if (e < cnt) {
            unsigned wd = lst[e];
            float cf = (float)(wd & 0xffffu) * S_DEQ;
            s += __expf((ui + vb[wd >> 16] - cf) * RCPE) * cf;
        }
    }
    s = waveAllSum(s);
    if (lane == 0) sh[w] = s;
    __syncthreads();
    if (threadIdx.x == 0) atomicAdd(&out[b], sh[0] + sh[1] + sh[2] + sh[3]);
}

extern "C" void kernel_launch(void* const* d_in, const int* in_sizes, int n_in,
                              void* d_out, int out_size, void* d_ws, size_t ws_size,
                              hipStream_t stream) {
    const float* a = (const float*)d_in[0];
    const float* b = (const float*)d_in[1];
    float* out = (float*)d_out;

    const size_t MBs = 1024ull * 1024ull;
    char* ws = (char*)d_ws;
    // [0,64M): C16.  [64M,76M): an/bn/partials (dead before selection).
    // [64M,96M): rlist (alias). [96M,128M): clist. [128M+): live vectors.
    unsigned short* C16 = (unsigned short*)ws;
    float* an    = (float*)(ws + 64 * MBs);
    float* bn    = (float*)(ws + 68 * MBs);
    float* rpart = (float*)(ws + 72 * MBs);
    float* cpart = (float*)(ws + 73 * MBs);
    unsigned* rminp = (unsigned*)(ws + 74 * MBs);
    unsigned* cminp = (unsigned*)(ws + 75 * MBs);
    unsigned* rlist = (unsigned*)(ws + 64 * MBs);   // 32 MB, alias of above
    unsigned* clist = (unsigned*)(ws + 96 * MBs);   // 32 MB
    char* tail = ws + 128 * MBs;
    size_t off = 0;
    const size_t szV = (size_t)NB * PP * 4;         // 64 KB
    int*   scnt    = (int*)(tail + off); off += (size_t)NB * PP * 4 * 4;  // 256 KB
    float* rowS    = (float*)(tail + off); off += szV;
    float* colS    = (float*)(tail + off); off += szV;
    unsigned* rowminp = (unsigned*)(tail + off); off += szV;
    unsigned* colminp = (unsigned*)(tail + off); off += szV;
    float* rowminf = (float*)(tail + off); off += szV;
    float* colminf = (float*)(tail + off); off += szV;
    float* cthresh = (float*)(tail + off); off += szV;
    float* elm     = (float*)(tail + off); off += szV;
    float* eln     = (float*)(tail + off); off += szV;
    float* u       = (float*)(tail + off); off += szV;
    float* v       = (float*)(tail + off); off += szV;
    float* du      = (float*)(tail + off); off += szV;
    int*   rcnt    = (int*)(tail + off); off += szV;
    int*   conv    = (int*)(tail + off); off += 64;
    if (ws_size < 128 * MBs + off) return;

    init_kernel<<<64, 256, 0, stream>>>(u, v, conv, out);
    norm_kernel<<<(2 * NB * PP) / 4, 256, 0, stream>>>(a, b, an, bn);
    cost_kernel<<<dim3(PP / 128, PP / 128, NB), 256, 0, stream>>>(an, bn, C16,
            rpart, cpart, rminp, cminp);
    combine_kernel<<<64, 256, 0, stream>>>(rpart, cpart, rminp, cminp,
            rowS, colS, rowminp, colminp);
    weights_kernel<<<16, 256, 0, stream>>>(rowS, colS, rowminp, colminp,
            elm, eln, rowminf, colminf, cthresh);
    row_select<<<NB * PP / 4, 256, 0, stream>>>(C16, colminf, rlist, rcnt);
    col_select<<<dim3(PP / 64, NB), 256, 0, stream>>>(C16, rowminf, cthresh, clist, scnt);
    for (int it = 0; it < TMAX; ++it) {
        u_kernel<<<NB * PP / 4, 256, 0, stream>>>(rlist, rcnt, v, elm, u, du, conv);
        v_kernel<<<NB * PP / 4, 256, 0, stream>>>(clist, scnt, u, eln, v, du, conv);
    }
    emd_kernel<<<NB * PP / 4, 256, 0, stream>>>(rlist, rcnt, u, v, out);
}